// Round 8
// baseline (405.554 us; speedup 1.0000x reference)
//
#include <hip/hip_runtime.h>
#include <hip/hip_bf16.h>

#define NN 50000
#define NE 800000
#define SCAN_G ((NN + 255) / 256)  // 196

typedef __attribute__((ext_vector_type(8))) short short8;
typedef __attribute__((ext_vector_type(4))) float f32x4;

__device__ inline float bf_lo(unsigned u) { u <<= 16; float f; __builtin_memcpy(&f, &u, 4); return f; }
__device__ inline float bf_hi(unsigned u) { u &= 0xffff0000u; float f; __builtin_memcpy(&f, &u, 4); return f; }
__device__ inline unsigned pack_bf16x2(float a, float b) {
    __hip_bfloat16 ba = __float2bfloat16(a), bb = __float2bfloat16(b);
    unsigned short ua, ub;
    __builtin_memcpy(&ua, &ba, 2);
    __builtin_memcpy(&ub, &bb, 2);
    return (unsigned)ua | ((unsigned)ub << 16);
}
__device__ inline __hip_bfloat16 f2bf(float a) { return __float2bfloat16(a); }

// ---------- prep: wpq bf16 [512 outcols][128 k] for the edge-MLP PQ GEMM ----------
__global__ void prep_wpq(const float* __restrict__ W3, __hip_bfloat16* __restrict__ wpq) {
    const int idx4 = (blockIdx.x * 256 + threadIdx.x) * 4;
    const int c = idx4 >> 7;
    const int k0 = idx4 & 127;
#pragma unroll
    for (int i = 0; i < 4; ++i) {
        const int k = k0 + i;
        const float v = (c < 256) ? W3[k * 256 + c] : W3[(128 + k) * 256 + (c - 256)];
        wpq[c * 128 + k] = __float2bfloat16(v);
    }
}

// ---------- prep: conv weights bf16 w12t[layer][256 col][128 k]; col<128 -> Wl, else Wr ----------
__global__ void prep_w12t(const float* __restrict__ W1l, const float* __restrict__ W1r,
                          const float* __restrict__ W2l, const float* __restrict__ W2r,
                          __hip_bfloat16* __restrict__ w12t) {
    const int idx = blockIdx.x * 256 + threadIdx.x;  // 65536 total
    const int layer = idx >> 15;
    const int c = (idx >> 7) & 255;
    const int k = idx & 127;
    const float* W = layer ? (c < 128 ? W2l : W2r) : (c < 128 ? W1l : W1r);
    w12t[idx] = __float2bfloat16(W[k * 128 + (c & 127)]);
}

// ---------- CSR build ----------
__global__ __launch_bounds__(256) void hist_kernel(const int* __restrict__ ei,
                                                   int* __restrict__ cnt) {
    for (int e = blockIdx.x * 256 + threadIdx.x; e < NE; e += gridDim.x * 256)
        atomicAdd(&cnt[ei[NE + e]], 1);
}

__global__ __launch_bounds__(256) void scan_blk(const int* __restrict__ cnt,
                                                int* __restrict__ off,
                                                int* __restrict__ bsum) {
    __shared__ int sm[256];
    const int t = threadIdx.x;
    const int i = blockIdx.x * 256 + t;
    const int v = (i < NN) ? cnt[i] : 0;
    sm[t] = v;
    __syncthreads();
    for (int d = 1; d < 256; d <<= 1) {
        const int add = (t >= d) ? sm[t - d] : 0;
        __syncthreads();
        sm[t] += add;
        __syncthreads();
    }
    if (i < NN) off[i] = sm[t] - v;
    if (t == 255) bsum[blockIdx.x] = sm[255];
}

__global__ __launch_bounds__(256) void scan_top(int* __restrict__ bsum) {
    __shared__ int sm[256];
    const int t = threadIdx.x;
    const int v = (t < SCAN_G) ? bsum[t] : 0;
    sm[t] = v;
    __syncthreads();
    for (int d = 1; d < 256; d <<= 1) {
        const int add = (t >= d) ? sm[t - d] : 0;
        __syncthreads();
        sm[t] += add;
        __syncthreads();
    }
    if (t < SCAN_G) bsum[t] = sm[t] - v;
}

__global__ __launch_bounds__(256) void scan_add(int* __restrict__ off,
                                                int* __restrict__ cursor,
                                                const int* __restrict__ bsum) {
    const int t = threadIdx.x;
    const int i = blockIdx.x * 256 + t;
    if (i < NN) {
        const int v = off[i] + bsum[blockIdx.x];
        off[i] = v;
        cursor[i] = v;
    }
    if (i == NN - 1) off[NN] = NE;
}

// fill sorted arrays: ssrc[p]=src (4B), sde[p]=(dst,eid) (8B) — 2 scattered stores
__global__ __launch_bounds__(256) void fill_kernel(const int* __restrict__ ei,
                                                   int* __restrict__ cursor,
                                                   int* __restrict__ ssrc,
                                                   int2* __restrict__ sde) {
    for (int e = blockIdx.x * 256 + threadIdx.x; e < NE; e += gridDim.x * 256) {
        const int d = ei[NE + e];
        const int p = atomicAdd(&cursor[d], 1);
        ssrc[p] = ei[e];
        sde[p] = make_int2(d, e);
    }
}

// ---------- projection GEMM: ob[n][0:128]=in[n]@Wl (y), ob[n][128:256]=in[n]@Wr (z) ----------
template <bool IN_F32>
__global__ __launch_bounds__(256) void proj_gemm(const void* __restrict__ inp,
                                                 const __hip_bfloat16* __restrict__ wt,
                                                 __hip_bfloat16* __restrict__ ob) {
    __shared__ __align__(16) char A[16384];  // A-tiles (64x256B), reused for C-chunks (16x528B)
    const int t = threadIdx.x;
    const int n0 = blockIdx.x * 64;
    {
        const int row = t >> 2, part = t & 3;
        const int node = n0 + row;
        const int sw = (row & 7) << 4;
        if (IN_F32) {
            const float* xp = (const float*)inp + (size_t)node * 128 + part * 32;
#pragma unroll
            for (int i = 0; i < 8; ++i) {
                uint2 w = make_uint2(0u, 0u);
                if (node < NN) {
                    const float4 v = *(const float4*)(xp + i * 4);
                    w.x = pack_bf16x2(v.x, v.y);
                    w.y = pack_bf16x2(v.z, v.w);
                }
                const int inner = part * 64 + i * 8;
                *(uint2*)(A + row * 256 + (inner ^ sw)) = w;
            }
        } else {
            const char* srcp = (const char*)((const __hip_bfloat16*)inp + (size_t)node * 128);
#pragma unroll
            for (int i = 0; i < 4; ++i) {
                const int inner = part * 64 + i * 16;
                uint4 v = make_uint4(0u, 0u, 0u, 0u);
                if (node < NN) v = *(const uint4*)(srcp + inner);
                *(uint4*)(A + row * 256 + (inner ^ sw)) = v;
            }
        }
    }
    __syncthreads();

    const int w = t >> 6, l = t & 63;
    const int lr = l & 15, lg = l >> 4;
    const int cb = w * 64;
    f32x4 acc[4][4] = {};
    for (int ks = 0; ks < 4; ++ks) {
        short8 af[4], bf[4];
        const int innerA = ks * 64 + lg * 16;
#pragma unroll
        for (int rt = 0; rt < 4; ++rt) {
            const int row = rt * 16 + lr;
            af[rt] = *(const short8*)(A + row * 256 + (innerA ^ ((row & 7) << 4)));
        }
        const int kidx = ks * 32 + lg * 8;
#pragma unroll
        for (int ct = 0; ct < 4; ++ct) {
            const int col = cb + ct * 16 + lr;
            bf[ct] = *(const short8*)(wt + col * 128 + kidx);
        }
#pragma unroll
        for (int rt = 0; rt < 4; ++rt)
#pragma unroll
            for (int ct = 0; ct < 4; ++ct)
                acc[rt][ct] = __builtin_amdgcn_mfma_f32_16x16x32_bf16(af[rt], bf[ct], acc[rt][ct], 0, 0, 0);
    }
#pragma unroll
    for (int rt = 0; rt < 4; ++rt) {
        __syncthreads();
#pragma unroll
        for (int ct = 0; ct < 4; ++ct) {
            const int col = cb + ct * 16 + lr;
#pragma unroll
            for (int j = 0; j < 4; ++j) {
                const int row = lg * 4 + j;
                *(__hip_bfloat16*)(A + row * 528 + col * 2) = f2bf(acc[rt][ct][j]);
            }
        }
        __syncthreads();
        const int row = t >> 4, cc = t & 15;
        const int node = n0 + rt * 16 + row;
        if (node < NN) {
#pragma unroll
            for (int pass = 0; pass < 2; ++pass) {
                const int byteoff = pass * 256 + cc * 16;
                *(uint4*)((char*)(ob + (size_t)node * 256) + byteoff) =
                    *(const uint4*)(A + row * 528 + byteoff);
            }
        }
    }
}

// ---------- gather-mean + bias + relu: h[n] = bf16(relu(mean_s y[s] + z[n] + b)) ----------
__global__ __launch_bounds__(256) void gather_fuse(const __hip_bfloat16* __restrict__ ob,
                                                   const int* __restrict__ off,
                                                   const int* __restrict__ ssrc,
                                                   const float* __restrict__ bl,
                                                   __hip_bfloat16* __restrict__ outp) {
    const int wv = threadIdx.x >> 6, lane = threadIdx.x & 63;
    const float2 bv = *(const float2*)&bl[lane * 2];
    for (int n = blockIdx.x * 4 + wv; n < NN; n += gridDim.x * 4) {
        const int b = off[n], e = off[n + 1];
        float a0 = 0.f, a1 = 0.f;
        int idx[8];
#pragma unroll
        for (int k = 0; k < 8; ++k) idx[k] = (b + k < e) ? ssrc[b + k] : 0;
        int i = b;
        for (; i + 8 <= e;) {
            unsigned u[8];
#pragma unroll
            for (int k = 0; k < 8; ++k)
                u[k] = *(const unsigned*)(ob + (size_t)idx[k] * 256 + lane * 2);
            i += 8;
#pragma unroll
            for (int k = 0; k < 8; ++k) idx[k] = (i + k < e) ? ssrc[i + k] : 0;
#pragma unroll
            for (int k = 0; k < 8; ++k) { a0 += bf_lo(u[k]); a1 += bf_hi(u[k]); }
        }
        for (int k = 0; i < e; ++i, ++k) {
            const unsigned u = *(const unsigned*)(ob + (size_t)idx[k] * 256 + lane * 2);
            a0 += bf_lo(u); a1 += bf_hi(u);
        }
        const float inv = 1.0f / fmaxf((float)(e - b), 1.0f);
        const unsigned uz = *(const unsigned*)(ob + (size_t)n * 256 + 128 + lane * 2);
        const float h0 = fmaxf(a0 * inv + bf_lo(uz) + bv.x, 0.0f);
        const float h1 = fmaxf(a1 * inv + bf_hi(uz) + bv.y, 0.0f);
        *(unsigned*)((char*)outp + (size_t)n * 256 + lane * 4) = pack_bf16x2(h0, h1);
    }
}

// ---------- PQ GEMM: pqb[n][0:256]=h2[n]@W3_top ; pqb[n][256:512]=h2[n]@W3_bot + b3 ----------
__global__ __launch_bounds__(256) void pq_gemm(const __hip_bfloat16* __restrict__ h2b,
                                               const __hip_bfloat16* __restrict__ wpq,
                                               const float* __restrict__ b3,
                                               __hip_bfloat16* __restrict__ pqb) {
    __shared__ __align__(16) char A[16640];  // A-tiles (64x256B), reused for C-chunks (16x1040B)
    const int t = threadIdx.x;
    const int n0 = blockIdx.x * 64;
    {
        const int row = t >> 2, part = t & 3;
        const int node = n0 + row;
        const int sw = (row & 7) << 4;
#pragma unroll
        for (int i = 0; i < 4; ++i) {
            const int inner = part * 64 + i * 16;
            uint4 v = make_uint4(0u, 0u, 0u, 0u);
            if (node < NN) v = *(const uint4*)((const char*)(h2b + node * 128) + inner);
            *(uint4*)(A + row * 256 + (inner ^ sw)) = v;
        }
    }
    __syncthreads();

    const int w = t >> 6, l = t & 63;
    const int lr = l & 15, lg = l >> 4;
    const int cb = w * 128;
    f32x4 acc[4][8] = {};
    for (int ks = 0; ks < 4; ++ks) {
        short8 af[4], bf[8];
        const int innerA = ks * 64 + lg * 16;
#pragma unroll
        for (int rt = 0; rt < 4; ++rt) {
            const int row = rt * 16 + lr;
            af[rt] = *(const short8*)(A + row * 256 + (innerA ^ ((row & 7) << 4)));
        }
        const int kidx = ks * 32 + lg * 8;
#pragma unroll
        for (int ct = 0; ct < 8; ++ct) {
            const int col = cb + ct * 16 + lr;
            bf[ct] = *(const short8*)(wpq + col * 128 + kidx);
        }
#pragma unroll
        for (int rt = 0; rt < 4; ++rt)
#pragma unroll
            for (int ct = 0; ct < 8; ++ct)
                acc[rt][ct] = __builtin_amdgcn_mfma_f32_16x16x32_bf16(af[rt], bf[ct], acc[rt][ct], 0, 0, 0);
    }
    float badd[8];
#pragma unroll
    for (int ct = 0; ct < 8; ++ct) {
        const int col = cb + ct * 16 + lr;
        badd[ct] = (col >= 256) ? b3[col - 256] : 0.f;
    }
#pragma unroll
    for (int rt = 0; rt < 4; ++rt) {
        __syncthreads();
#pragma unroll
        for (int ct = 0; ct < 8; ++ct) {
            const int col = cb + ct * 16 + lr;
#pragma unroll
            for (int j = 0; j < 4; ++j) {
                const int row = lg * 4 + j;
                *(__hip_bfloat16*)(A + row * 1040 + col * 2) = f2bf(acc[rt][ct][j] + badd[ct]);
            }
        }
        __syncthreads();
        const int row = t >> 4, cc = t & 15;
        const int node = n0 + rt * 16 + row;
        if (node < NN) {
#pragma unroll
            for (int pass = 0; pass < 4; ++pass) {
                const int byteoff = pass * 256 + cc * 16;
                *(uint4*)((char*)(pqb + (size_t)node * 512) + byteoff) =
                    *(const uint4*)(A + row * 1040 + byteoff);
            }
        }
    }
}

// ---------- edge: out[eid] = W4 . relu(P[src] + Q'[dst]) + b4, 2 edges per 8-lane group ----------
__global__ __launch_bounds__(256) void edge_kernel(const int* __restrict__ ssrc,
                                                   const int2* __restrict__ sde,
                                                   const __hip_bfloat16* __restrict__ pqb,
                                                   const float* __restrict__ W4,
                                                   const float* __restrict__ b4,
                                                   float* __restrict__ out) {
    const int i = threadIdx.x & 7;
    const int g = threadIdx.x >> 3;  // 32 groups; each handles an edge pair
    float w4r[4][8];
#pragma unroll
    for (int j = 0; j < 4; ++j)
#pragma unroll
        for (int u = 0; u < 8; ++u)
            w4r[j][u] = W4[i * 8 + j * 64 + u];
    const float b4v = b4[0];
    for (int p = blockIdx.x * 64 + g * 2; p < NE; p += gridDim.x * 64) {
        const int s0 = ssrc[p], s1 = ssrc[p + 1];
        const int2 de0 = sde[p], de1 = sde[p + 1];
        const char* P0 = (const char*)(pqb + (size_t)s0 * 512 + i * 8);
        const char* Q0 = (const char*)(pqb + (size_t)de0.x * 512 + 256 + i * 8);
        const char* P1 = (const char*)(pqb + (size_t)s1 * 512 + i * 8);
        const char* Q1 = (const char*)(pqb + (size_t)de1.x * 512 + 256 + i * 8);
        uint4 pv0[4], qv0[4], pv1[4], qv1[4];
#pragma unroll
        for (int j = 0; j < 4; ++j) {
            pv0[j] = *(const uint4*)(P0 + j * 128);
            qv0[j] = *(const uint4*)(Q0 + j * 128);
            pv1[j] = *(const uint4*)(P1 + j * 128);
            qv1[j] = *(const uint4*)(Q1 + j * 128);
        }
        float acc0 = 0.f, acc1 = 0.f;
#pragma unroll
        for (int j = 0; j < 4; ++j) {
            const unsigned pa0[4] = {pv0[j].x, pv0[j].y, pv0[j].z, pv0[j].w};
            const unsigned qa0[4] = {qv0[j].x, qv0[j].y, qv0[j].z, qv0[j].w};
            const unsigned pa1[4] = {pv1[j].x, pv1[j].y, pv1[j].z, pv1[j].w};
            const unsigned qa1[4] = {qv1[j].x, qv1[j].y, qv1[j].z, qv1[j].w};
#pragma unroll
            for (int q4 = 0; q4 < 4; ++q4) {
                const float h0l = fmaxf(bf_lo(pa0[q4]) + bf_lo(qa0[q4]), 0.f);
                const float h0h = fmaxf(bf_hi(pa0[q4]) + bf_hi(qa0[q4]), 0.f);
                acc0 = fmaf(h0l, w4r[j][q4 * 2], acc0);
                acc0 = fmaf(h0h, w4r[j][q4 * 2 + 1], acc0);
                const float h1l = fmaxf(bf_lo(pa1[q4]) + bf_lo(qa1[q4]), 0.f);
                const float h1h = fmaxf(bf_hi(pa1[q4]) + bf_hi(qa1[q4]), 0.f);
                acc1 = fmaf(h1l, w4r[j][q4 * 2], acc1);
                acc1 = fmaf(h1h, w4r[j][q4 * 2 + 1], acc1);
            }
        }
#pragma unroll
        for (int m = 1; m <= 4; m <<= 1) {
            acc0 += __shfl_xor(acc0, m);
            acc1 += __shfl_xor(acc1, m);
        }
        if (i == 0) {
            out[de0.y] = acc0 + b4v;
            out[de1.y] = acc1 + b4v;
        }
    }
}

extern "C" void kernel_launch(void* const* d_in, const int* in_sizes, int n_in,
                              void* d_out, int out_size, void* d_ws, size_t ws_size,
                              hipStream_t stream) {
    const float* x   = (const float*)d_in[0];
    const int* ei    = (const int*)d_in[1];
    const float* W1l = (const float*)d_in[2];
    const float* b1l = (const float*)d_in[3];
    const float* W1r = (const float*)d_in[4];
    const float* W2l = (const float*)d_in[5];
    const float* b2l = (const float*)d_in[6];
    const float* W2r = (const float*)d_in[7];
    const float* W3  = (const float*)d_in[8];
    const float* b3  = (const float*)d_in[9];
    const float* W4  = (const float*)d_in[10];
    const float* b4  = (const float*)d_in[11];
    float* out = (float*)d_out;

    char* ws = (char*)d_ws;
    int* cnt            = (int*)(ws);                        // 200 KB
    int* off            = (int*)(ws + 200704);
    int* cursor         = (int*)(ws + 401408);               // + bsum at cursor+NN
    int* ssrc           = (int*)(ws + 602112);               // 3.2 MB
    int2* sde           = (int2*)(ws + 3802112);             // 6.4 MB (dst,eid)
    __hip_bfloat16* pqb = (__hip_bfloat16*)(ws + 10202112);  // 51.2 MB (overlays h1b+ob)
    __hip_bfloat16* h1b = (__hip_bfloat16*)(ws + 23002112);  // 12.8 MB (dead before pq_gemm)
    __hip_bfloat16* ob  = (__hip_bfloat16*)(ws + 35802112);  // 25.6 MB (dead before pq_gemm)
    __hip_bfloat16* h2b = (__hip_bfloat16*)(ws + 61402112);  // 12.8 MB
    __hip_bfloat16* wpq = (__hip_bfloat16*)(ws + 74202112);  // 128 KB
    __hip_bfloat16* w12t= (__hip_bfloat16*)(ws + 74333184);  // 128 KB

    hipMemsetAsync(cnt, 0, NN * sizeof(int), stream);
    hist_kernel<<<1024, 256, 0, stream>>>(ei, cnt);
    scan_blk<<<SCAN_G, 256, 0, stream>>>(cnt, off, cursor + NN);
    scan_top<<<1, 256, 0, stream>>>(cursor + NN);
    scan_add<<<SCAN_G, 256, 0, stream>>>(off, cursor, cursor + NN);
    fill_kernel<<<1024, 256, 0, stream>>>(ei, cursor, ssrc, sde);
    prep_wpq<<<64, 256, 0, stream>>>(W3, wpq);
    prep_w12t<<<256, 256, 0, stream>>>(W1l, W1r, W2l, W2r, w12t);

    proj_gemm<true><<<(NN + 63) / 64, 256, 0, stream>>>((const void*)x, w12t, ob);
    gather_fuse<<<2048, 256, 0, stream>>>(ob, off, ssrc, b1l, h1b);
    proj_gemm<false><<<(NN + 63) / 64, 256, 0, stream>>>((const void*)h1b, w12t + 256 * 128, ob);
    gather_fuse<<<2048, 256, 0, stream>>>(ob, off, ssrc, b2l, h2b);
    pq_gemm<<<(NN + 63) / 64, 256, 0, stream>>>(h2b, wpq, b3, pqb);
    edge_kernel<<<2048, 256, 0, stream>>>(ssrc, sde, pqb, W4, b4, out);
}

// Round 9
// 395.576 us; speedup vs baseline: 1.0252x; 1.0252x over previous
//
#include <hip/hip_runtime.h>
#include <hip/hip_bf16.h>

#define NN 50000
#define NE 800000
#define SCAN_G ((NN + 255) / 256)  // 196

typedef __attribute__((ext_vector_type(8))) short short8;
typedef __attribute__((ext_vector_type(4))) float f32x4;

__device__ inline float bf_lo(unsigned u) { u <<= 16; float f; __builtin_memcpy(&f, &u, 4); return f; }
__device__ inline float bf_hi(unsigned u) { u &= 0xffff0000u; float f; __builtin_memcpy(&f, &u, 4); return f; }
__device__ inline unsigned pack_bf16x2(float a, float b) {
    __hip_bfloat16 ba = __float2bfloat16(a), bb = __float2bfloat16(b);
    unsigned short ua, ub;
    __builtin_memcpy(&ua, &ba, 2);
    __builtin_memcpy(&ub, &bb, 2);
    return (unsigned)ua | ((unsigned)ub << 16);
}
__device__ inline __hip_bfloat16 f2bf(float a) { return __float2bfloat16(a); }

// ---------- fused prep: zero cnt | wpq bf16 [512][128] | w12t bf16 [2][256][128] ----------
__global__ __launch_bounds__(256) void prep_all(const float* __restrict__ W3,
                                                __hip_bfloat16* __restrict__ wpq,
                                                const float* __restrict__ W1l,
                                                const float* __restrict__ W1r,
                                                const float* __restrict__ W2l,
                                                const float* __restrict__ W2r,
                                                __hip_bfloat16* __restrict__ w12t,
                                                int* __restrict__ cnt) {
    const int b = blockIdx.x;
    if (b < SCAN_G) {
        const int i = b * 256 + threadIdx.x;
        if (i < NN) cnt[i] = 0;
    } else if (b < SCAN_G + 64) {
        const int idx4 = ((b - SCAN_G) * 256 + threadIdx.x) * 4;
        const int c = idx4 >> 7;
        const int k0 = idx4 & 127;
#pragma unroll
        for (int i = 0; i < 4; ++i) {
            const int k = k0 + i;
            const float v = (c < 256) ? W3[k * 256 + c] : W3[(128 + k) * 256 + (c - 256)];
            wpq[c * 128 + k] = __float2bfloat16(v);
        }
    } else {
        const int idx = (b - SCAN_G - 64) * 256 + threadIdx.x;  // 65536 total
        const int layer = idx >> 15;
        const int c = (idx >> 7) & 255;
        const int k = idx & 127;
        const float* W = layer ? (c < 128 ? W2l : W2r) : (c < 128 ? W1l : W1r);
        w12t[idx] = __float2bfloat16(W[k * 128 + (c & 127)]);
    }
}

// ---------- CSR build ----------
__global__ __launch_bounds__(256) void hist_kernel(const int* __restrict__ ei,
                                                   int* __restrict__ cnt) {
    for (int e = blockIdx.x * 256 + threadIdx.x; e < NE; e += gridDim.x * 256)
        atomicAdd(&cnt[ei[NE + e]], 1);
}

__global__ __launch_bounds__(256) void scan_blk(const int* __restrict__ cnt,
                                                int* __restrict__ off,
                                                int* __restrict__ bsum) {
    __shared__ int sm[256];
    const int t = threadIdx.x;
    const int i = blockIdx.x * 256 + t;
    const int v = (i < NN) ? cnt[i] : 0;
    sm[t] = v;
    __syncthreads();
    for (int d = 1; d < 256; d <<= 1) {
        const int add = (t >= d) ? sm[t - d] : 0;
        __syncthreads();
        sm[t] += add;
        __syncthreads();
    }
    if (i < NN) off[i] = sm[t] - v;
    if (t == 255) bsum[blockIdx.x] = sm[255];
}

// fused top-scan + add-back: each block redundantly sums bsum[0..blockIdx)
__global__ __launch_bounds__(256) void scan_add(int* __restrict__ off,
                                                int* __restrict__ cursor,
                                                const int* __restrict__ bsum) {
    __shared__ int red[256];
    const int t = threadIdx.x;
    int s = 0;
    for (int j = t; j < blockIdx.x; j += 256) s += bsum[j];
    red[t] = s;
    __syncthreads();
    for (int d = 128; d; d >>= 1) {
        if (t < d) red[t] += red[t + d];
        __syncthreads();
    }
    const int base = red[0];
    const int i = blockIdx.x * 256 + t;
    if (i < NN) {
        const int v = off[i] + base;
        off[i] = v;
        cursor[i] = v;
    }
    if (i == NN - 1) off[NN] = NE;
}

// fill sorted arrays: ssrc[p]=src (4B), sde[p]=(dst,eid) (8B)
__global__ __launch_bounds__(256) void fill_kernel(const int* __restrict__ ei,
                                                   int* __restrict__ cursor,
                                                   int* __restrict__ ssrc,
                                                   int2* __restrict__ sde) {
    for (int e = blockIdx.x * 256 + threadIdx.x; e < NE; e += gridDim.x * 256) {
        const int d = ei[NE + e];
        const int p = atomicAdd(&cursor[d], 1);
        ssrc[p] = ei[e];
        sde[p] = make_int2(d, e);
    }
}

// ---------- projection GEMM: ob[n][0:128]=in[n]@Wl (y), ob[n][128:256]=in[n]@Wr (z) ----------
template <bool IN_F32>
__global__ __launch_bounds__(256) void proj_gemm(const void* __restrict__ inp,
                                                 const __hip_bfloat16* __restrict__ wt,
                                                 __hip_bfloat16* __restrict__ ob) {
    __shared__ __align__(16) char A[16384];  // A-tiles (64x256B), reused for C-chunks (16x528B)
    const int t = threadIdx.x;
    const int n0 = blockIdx.x * 64;
    {
        const int row = t >> 2, part = t & 3;
        const int node = n0 + row;
        const int sw = (row & 7) << 4;
        if (IN_F32) {
            const float* xp = (const float*)inp + (size_t)node * 128 + part * 32;
#pragma unroll
            for (int i = 0; i < 8; ++i) {
                uint2 w = make_uint2(0u, 0u);
                if (node < NN) {
                    const float4 v = *(const float4*)(xp + i * 4);
                    w.x = pack_bf16x2(v.x, v.y);
                    w.y = pack_bf16x2(v.z, v.w);
                }
                const int inner = part * 64 + i * 8;
                *(uint2*)(A + row * 256 + (inner ^ sw)) = w;
            }
        } else {
            const char* srcp = (const char*)((const __hip_bfloat16*)inp + (size_t)node * 128);
#pragma unroll
            for (int i = 0; i < 4; ++i) {
                const int inner = part * 64 + i * 16;
                uint4 v = make_uint4(0u, 0u, 0u, 0u);
                if (node < NN) v = *(const uint4*)(srcp + inner);
                *(uint4*)(A + row * 256 + (inner ^ sw)) = v;
            }
        }
    }
    __syncthreads();

    const int w = t >> 6, l = t & 63;
    const int lr = l & 15, lg = l >> 4;
    const int cb = w * 64;
    f32x4 acc[4][4] = {};
    for (int ks = 0; ks < 4; ++ks) {
        short8 af[4], bf[4];
        const int innerA = ks * 64 + lg * 16;
#pragma unroll
        for (int rt = 0; rt < 4; ++rt) {
            const int row = rt * 16 + lr;
            af[rt] = *(const short8*)(A + row * 256 + (innerA ^ ((row & 7) << 4)));
        }
        const int kidx = ks * 32 + lg * 8;
#pragma unroll
        for (int ct = 0; ct < 4; ++ct) {
            const int col = cb + ct * 16 + lr;
            bf[ct] = *(const short8*)(wt + col * 128 + kidx);
        }
#pragma unroll
        for (int rt = 0; rt < 4; ++rt)
#pragma unroll
            for (int ct = 0; ct < 4; ++ct)
                acc[rt][ct] = __builtin_amdgcn_mfma_f32_16x16x32_bf16(af[rt], bf[ct], acc[rt][ct], 0, 0, 0);
    }
#pragma unroll
    for (int rt = 0; rt < 4; ++rt) {
        __syncthreads();
#pragma unroll
        for (int ct = 0; ct < 4; ++ct) {
            const int col = cb + ct * 16 + lr;
#pragma unroll
            for (int j = 0; j < 4; ++j) {
                const int row = lg * 4 + j;
                *(__hip_bfloat16*)(A + row * 528 + col * 2) = f2bf(acc[rt][ct][j]);
            }
        }
        __syncthreads();
        const int row = t >> 4, cc = t & 15;
        const int node = n0 + rt * 16 + row;
        if (node < NN) {
#pragma unroll
            for (int pass = 0; pass < 2; ++pass) {
                const int byteoff = pass * 256 + cc * 16;
                *(uint4*)((char*)(ob + (size_t)node * 256) + byteoff) =
                    *(const uint4*)(A + row * 528 + byteoff);
            }
        }
    }
}

// ---------- gather-mean + bias + relu: h[n] = bf16(relu(mean_s y[s] + z[n] + b)) ----------
__global__ __launch_bounds__(256) void gather_fuse(const __hip_bfloat16* __restrict__ ob,
                                                   const int* __restrict__ off,
                                                   const int* __restrict__ ssrc,
                                                   const float* __restrict__ bl,
                                                   __hip_bfloat16* __restrict__ outp) {
    const int wv = threadIdx.x >> 6, lane = threadIdx.x & 63;
    const float2 bv = *(const float2*)&bl[lane * 2];
    for (int n = blockIdx.x * 4 + wv; n < NN; n += gridDim.x * 4) {
        const int b = off[n], e = off[n + 1];
        float a0 = 0.f, a1 = 0.f;
        int i = b;
        int s0 = (i + 0 < e) ? ssrc[i + 0] : 0;
        int s1 = (i + 1 < e) ? ssrc[i + 1] : 0;
        int s2 = (i + 2 < e) ? ssrc[i + 2] : 0;
        int s3 = (i + 3 < e) ? ssrc[i + 3] : 0;
        for (; i + 4 <= e;) {
            const unsigned u0 = *(const unsigned*)(ob + (size_t)s0 * 256 + lane * 2);
            const unsigned u1 = *(const unsigned*)(ob + (size_t)s1 * 256 + lane * 2);
            const unsigned u2 = *(const unsigned*)(ob + (size_t)s2 * 256 + lane * 2);
            const unsigned u3 = *(const unsigned*)(ob + (size_t)s3 * 256 + lane * 2);
            i += 4;
            s0 = (i + 0 < e) ? ssrc[i + 0] : 0;
            s1 = (i + 1 < e) ? ssrc[i + 1] : 0;
            s2 = (i + 2 < e) ? ssrc[i + 2] : 0;
            s3 = (i + 3 < e) ? ssrc[i + 3] : 0;
            a0 += bf_lo(u0) + bf_lo(u1) + bf_lo(u2) + bf_lo(u3);
            a1 += bf_hi(u0) + bf_hi(u1) + bf_hi(u2) + bf_hi(u3);
        }
        if (i < e) {
            const unsigned u = *(const unsigned*)(ob + (size_t)s0 * 256 + lane * 2);
            a0 += bf_lo(u); a1 += bf_hi(u); ++i;
            if (i < e) {
                const unsigned u1_ = *(const unsigned*)(ob + (size_t)s1 * 256 + lane * 2);
                a0 += bf_lo(u1_); a1 += bf_hi(u1_); ++i;
                if (i < e) {
                    const unsigned u2_ = *(const unsigned*)(ob + (size_t)s2 * 256 + lane * 2);
                    a0 += bf_lo(u2_); a1 += bf_hi(u2_);
                }
            }
        }
        const float inv = 1.0f / fmaxf((float)(e - b), 1.0f);
        const unsigned uz = *(const unsigned*)(ob + (size_t)n * 256 + 128 + lane * 2);
        const float h0 = fmaxf(a0 * inv + bf_lo(uz) + bv.x, 0.0f);
        const float h1 = fmaxf(a1 * inv + bf_hi(uz) + bv.y, 0.0f);
        *(unsigned*)((char*)outp + (size_t)n * 256 + lane * 4) = pack_bf16x2(h0, h1);
    }
}

// ---------- PQ GEMM: pqb[n][0:256]=h2[n]@W3_top ; pqb[n][256:512]=h2[n]@W3_bot + b3 ----------
__global__ __launch_bounds__(256) void pq_gemm(const __hip_bfloat16* __restrict__ h2b,
                                               const __hip_bfloat16* __restrict__ wpq,
                                               const float* __restrict__ b3,
                                               __hip_bfloat16* __restrict__ pqb) {
    __shared__ __align__(16) char A[16640];  // A-tiles (64x256B), reused for C-chunks (16x1040B)
    const int t = threadIdx.x;
    const int n0 = blockIdx.x * 64;
    {
        const int row = t >> 2, part = t & 3;
        const int node = n0 + row;
        const int sw = (row & 7) << 4;
#pragma unroll
        for (int i = 0; i < 4; ++i) {
            const int inner = part * 64 + i * 16;
            uint4 v = make_uint4(0u, 0u, 0u, 0u);
            if (node < NN) v = *(const uint4*)((const char*)(h2b + node * 128) + inner);
            *(uint4*)(A + row * 256 + (inner ^ sw)) = v;
        }
    }
    __syncthreads();

    const int w = t >> 6, l = t & 63;
    const int lr = l & 15, lg = l >> 4;
    const int cb = w * 128;
    f32x4 acc[4][8] = {};
    for (int ks = 0; ks < 4; ++ks) {
        short8 af[4], bf[8];
        const int innerA = ks * 64 + lg * 16;
#pragma unroll
        for (int rt = 0; rt < 4; ++rt) {
            const int row = rt * 16 + lr;
            af[rt] = *(const short8*)(A + row * 256 + (innerA ^ ((row & 7) << 4)));
        }
        const int kidx = ks * 32 + lg * 8;
#pragma unroll
        for (int ct = 0; ct < 8; ++ct) {
            const int col = cb + ct * 16 + lr;
            bf[ct] = *(const short8*)(wpq + col * 128 + kidx);
        }
#pragma unroll
        for (int rt = 0; rt < 4; ++rt)
#pragma unroll
            for (int ct = 0; ct < 8; ++ct)
                acc[rt][ct] = __builtin_amdgcn_mfma_f32_16x16x32_bf16(af[rt], bf[ct], acc[rt][ct], 0, 0, 0);
    }
    float badd[8];
#pragma unroll
    for (int ct = 0; ct < 8; ++ct) {
        const int col = cb + ct * 16 + lr;
        badd[ct] = (col >= 256) ? b3[col - 256] : 0.f;
    }
#pragma unroll
    for (int rt = 0; rt < 4; ++rt) {
        __syncthreads();
#pragma unroll
        for (int ct = 0; ct < 8; ++ct) {
            const int col = cb + ct * 16 + lr;
#pragma unroll
            for (int j = 0; j < 4; ++j) {
                const int row = lg * 4 + j;
                *(__hip_bfloat16*)(A + row * 1040 + col * 2) = f2bf(acc[rt][ct][j] + badd[ct]);
            }
        }
        __syncthreads();
        const int row = t >> 4, cc = t & 15;
        const int node = n0 + rt * 16 + row;
        if (node < NN) {
#pragma unroll
            for (int pass = 0; pass < 4; ++pass) {
                const int byteoff = pass * 256 + cc * 16;
                *(uint4*)((char*)(pqb + (size_t)node * 512) + byteoff) =
                    *(const uint4*)(A + row * 1040 + byteoff);
            }
        }
    }
}

// ---------- edge: out[eid] = W4 . relu(P[src] + Q'[dst]) + b4, 2 edges per 8-lane group ----------
__global__ __launch_bounds__(256) void edge_kernel(const int* __restrict__ ssrc,
                                                   const int2* __restrict__ sde,
                                                   const __hip_bfloat16* __restrict__ pqb,
                                                   const float* __restrict__ W4,
                                                   const float* __restrict__ b4,
                                                   float* __restrict__ out) {
    const int i = threadIdx.x & 7;
    const int g = threadIdx.x >> 3;
    float w4r[4][8];
#pragma unroll
    for (int j = 0; j < 4; ++j)
#pragma unroll
        for (int u = 0; u < 8; ++u)
            w4r[j][u] = W4[i * 8 + j * 64 + u];
    const float b4v = b4[0];
    for (int p = blockIdx.x * 64 + g * 2; p < NE; p += gridDim.x * 64) {
        const int s0 = ssrc[p], s1 = ssrc[p + 1];
        const int2 de0 = sde[p], de1 = sde[p + 1];
        const char* P0 = (const char*)(pqb + (size_t)s0 * 512 + i * 8);
        const char* Q0 = (const char*)(pqb + (size_t)de0.x * 512 + 256 + i * 8);
        const char* P1 = (const char*)(pqb + (size_t)s1 * 512 + i * 8);
        const char* Q1 = (const char*)(pqb + (size_t)de1.x * 512 + 256 + i * 8);
        uint4 pv0[4], qv0[4], pv1[4], qv1[4];
#pragma unroll
        for (int j = 0; j < 4; ++j) {
            pv0[j] = *(const uint4*)(P0 + j * 128);
            qv0[j] = *(const uint4*)(Q0 + j * 128);
            pv1[j] = *(const uint4*)(P1 + j * 128);
            qv1[j] = *(const uint4*)(Q1 + j * 128);
        }
        float acc0 = 0.f, acc1 = 0.f;
#pragma unroll
        for (int j = 0; j < 4; ++j) {
            const unsigned pa0[4] = {pv0[j].x, pv0[j].y, pv0[j].z, pv0[j].w};
            const unsigned qa0[4] = {qv0[j].x, qv0[j].y, qv0[j].z, qv0[j].w};
            const unsigned pa1[4] = {pv1[j].x, pv1[j].y, pv1[j].z, pv1[j].w};
            const unsigned qa1[4] = {qv1[j].x, qv1[j].y, qv1[j].z, qv1[j].w};
#pragma unroll
            for (int q4 = 0; q4 < 4; ++q4) {
                const float h0l = fmaxf(bf_lo(pa0[q4]) + bf_lo(qa0[q4]), 0.f);
                const float h0h = fmaxf(bf_hi(pa0[q4]) + bf_hi(qa0[q4]), 0.f);
                acc0 = fmaf(h0l, w4r[j][q4 * 2], acc0);
                acc0 = fmaf(h0h, w4r[j][q4 * 2 + 1], acc0);
                const float h1l = fmaxf(bf_lo(pa1[q4]) + bf_lo(qa1[q4]), 0.f);
                const float h1h = fmaxf(bf_hi(pa1[q4]) + bf_hi(qa1[q4]), 0.f);
                acc1 = fmaf(h1l, w4r[j][q4 * 2], acc1);
                acc1 = fmaf(h1h, w4r[j][q4 * 2 + 1], acc1);
            }
        }
#pragma unroll
        for (int m = 1; m <= 4; m <<= 1) {
            acc0 += __shfl_xor(acc0, m);
            acc1 += __shfl_xor(acc1, m);
        }
        if (i == 0) {
            out[de0.y] = acc0 + b4v;
            out[de1.y] = acc1 + b4v;
        }
    }
}

extern "C" void kernel_launch(void* const* d_in, const int* in_sizes, int n_in,
                              void* d_out, int out_size, void* d_ws, size_t ws_size,
                              hipStream_t stream) {
    const float* x   = (const float*)d_in[0];
    const int* ei    = (const int*)d_in[1];
    const float* W1l = (const float*)d_in[2];
    const float* b1l = (const float*)d_in[3];
    const float* W1r = (const float*)d_in[4];
    const float* W2l = (const float*)d_in[5];
    const float* b2l = (const float*)d_in[6];
    const float* W2r = (const float*)d_in[7];
    const float* W3  = (const float*)d_in[8];
    const float* b3  = (const float*)d_in[9];
    const float* W4  = (const float*)d_in[10];
    const float* b4  = (const float*)d_in[11];
    float* out = (float*)d_out;

    char* ws = (char*)d_ws;
    int* cnt            = (int*)(ws);                        // 200 KB
    int* off            = (int*)(ws + 200704);
    int* cursor         = (int*)(ws + 401408);               // bsum at cursor+NN (dead before fill)
    int* bsum           = cursor + NN;
    int* ssrc           = (int*)(ws + 602112);               // 3.2 MB
    int2* sde           = (int2*)(ws + 3802112);             // 6.4 MB (dst,eid)
    __hip_bfloat16* pqb = (__hip_bfloat16*)(ws + 10202112);  // 51.2 MB (overlays h1b+ob)
    __hip_bfloat16* h1b = (__hip_bfloat16*)(ws + 23002112);  // 12.8 MB (dead before pq_gemm)
    __hip_bfloat16* ob  = (__hip_bfloat16*)(ws + 35802112);  // 25.6 MB (dead before pq_gemm)
    __hip_bfloat16* h2b = (__hip_bfloat16*)(ws + 61402112);  // 12.8 MB
    __hip_bfloat16* wpq = (__hip_bfloat16*)(ws + 74202112);  // 128 KB
    __hip_bfloat16* w12t= (__hip_bfloat16*)(ws + 74333184);  // 128 KB

    prep_all<<<SCAN_G + 64 + 256, 256, 0, stream>>>(W3, wpq, W1l, W1r, W2l, W2r, w12t, cnt);
    hist_kernel<<<1024, 256, 0, stream>>>(ei, cnt);
    scan_blk<<<SCAN_G, 256, 0, stream>>>(cnt, off, bsum);
    scan_add<<<SCAN_G, 256, 0, stream>>>(off, cursor, bsum);
    fill_kernel<<<1024, 256, 0, stream>>>(ei, cursor, ssrc, sde);

    proj_gemm<true><<<(NN + 63) / 64, 256, 0, stream>>>((const void*)x, w12t, ob);
    gather_fuse<<<2048, 256, 0, stream>>>(ob, off, ssrc, b1l, h1b);
    proj_gemm<false><<<(NN + 63) / 64, 256, 0, stream>>>((const void*)h1b, w12t + 256 * 128, ob);
    gather_fuse<<<2048, 256, 0, stream>>>(ob, off, ssrc, b2l, h2b);
    pq_gemm<<<(NN + 63) / 64, 256, 0, stream>>>(h2b, wpq, b3, pqb);
    edge_kernel<<<2048, 256, 0, stream>>>(ssrc, sde, pqb, W4, b4, out);
}